// Round 16
// baseline (144.980 us; speedup 1.0000x reference)
//
#include <hip/hip_runtime.h>
#include <math.h>

#define BB   32
#define CIN  16
#define HH   64
#define SS   128

// ---------------------------------------------------------------------------
// R16 = R15 byte-identical, but `front` is launched 9x (8 extra idempotent
// replays) purely to measure front's marginal cost: (dur - 50.4)/8.
// ---------------------------------------------------------------------------

__global__ __launch_bounds__(256) void prep(
    const float* __restrict__ w11, const float* __restrict__ w21,
    const float* __restrict__ w12, const float* __restrict__ w22,
    const float* __restrict__ w31, const float* __restrict__ wf,
    const float* __restrict__ bf,
    const float* __restrict__ b11, const float* __restrict__ b21,
    const float* __restrict__ b12, const float* __restrict__ b22,
    const float* __restrict__ b31,
    double* __restrict__ T, double* __restrict__ Be)
{
    __shared__ float  wfl[192 * 65];
    __shared__ double W1s[4][64];
    __shared__ double W2s[4][64];
    __shared__ double SW1s[64][3];
    __shared__ double SW2s[64][5];

    const int tid = threadIdx.x;
    const int bx  = blockIdx.x;

    for (int e = tid; e < 12288; e += 256) {
        int n = e / 192, m = e - n * 192;
        wfl[m * 65 + n] = wf[e];
    }

    if (bx < 44) {
        const int slot = tid >> 6, n = tid & 63;
        const int k = bx * 4 + slot, c = k / 11, ti = k % 11;
        const bool p1 = (ti == 2 || ti == 5 || ti == 8);
        const bool p2 = (ti == 0 || ti == 1 || ti == 5 || ti == 9 || ti == 10);
        const bool p3 = (ti >= 3 && ti <= 7);
        if (p1) {
            int t = (ti - 2) / 3;
            double s0 = 0, s1 = 0;
            #pragma unroll
            for (int mm = 0; mm < 64; mm += 2) {
                s0 += (double)w12[(n*64+mm)*3+t]   * (double)w11[mm*16+c];
                s1 += (double)w12[(n*64+mm+1)*3+t] * (double)w11[(mm+1)*16+c];
            }
            W1s[slot][n] = s0 + s1;
        }
        if (p2) {
            int u = (ti == 0) ? 0 : (ti == 1) ? 1 : (ti == 5) ? 2 : (ti == 9) ? 3 : 4;
            double s0 = 0, s1 = 0;
            #pragma unroll
            for (int mm = 0; mm < 64; mm += 2) {
                s0 += (double)w22[(n*64+mm)*5+u]   * (double)w21[mm*16+c];
                s1 += (double)w22[(n*64+mm+1)*5+u] * (double)w21[(mm+1)*16+c];
            }
            W2s[slot][n] = s0 + s1;
        }
        __syncthreads();
        double a0 = 0, a1 = 0;
        if (p1) {
            #pragma unroll
            for (int m = 0; m < 64; m += 2) {
                a0 += (double)wfl[m*65+n]     * W1s[slot][m];
                a1 += (double)wfl[(m+1)*65+n] * W1s[slot][m+1];
            }
        }
        if (p2) {
            #pragma unroll
            for (int m = 0; m < 64; m += 2) {
                a0 += (double)wfl[(64+m)*65+n]   * W2s[slot][m];
                a1 += (double)wfl[(64+m+1)*65+n] * W2s[slot][m+1];
            }
        }
        if (p3) {
            int v = ti - 3;
            #pragma unroll
            for (int m = 0; m < 64; m += 2) {
                a0 += (double)wfl[(128+m)*65+n]   * (double)w31[(m*16+c)*5+v];
                a1 += (double)wfl[(128+m+1)*65+n] * (double)w31[((m+1)*16+c)*5+v];
            }
        }
        T[k * 64 + n] = a0 + a1;
    } else {
        for (int q = tid; q < 512; q += 256) {
            if (q < 192) {
                int m = q / 3, t = q - 3 * m;
                double s0 = 0, s1 = 0;
                #pragma unroll
                for (int mm = 0; mm < 64; mm += 2) {
                    s0 += (double)w12[(m*64+mm)*3+t]   * (double)b11[mm];
                    s1 += (double)w12[(m*64+mm+1)*3+t] * (double)b11[mm+1];
                }
                SW1s[m][t] = s0 + s1;
            } else {
                int q2 = q - 192; int m = q2 / 5, u = q2 - 5 * m;
                double s0 = 0, s1 = 0;
                #pragma unroll
                for (int mm = 0; mm < 64; mm += 2) {
                    s0 += (double)w22[(m*64+mm)*5+u]   * (double)b21[mm];
                    s1 += (double)w22[(m*64+mm+1)*5+u] * (double)b21[mm+1];
                }
                SW2s[m][u] = s0 + s1;
            }
        }
        __syncthreads();
        int j = (bx - 44) * 256 + tid;
        int n = tid & 63, p = j >> 6;
        double base = (double)bf[n];
        double d10 = 0, d12 = 0, d20 = 0, d21 = 0, d23 = 0, d24 = 0;
        #pragma unroll
        for (int m = 0; m < 64; ++m) {
            double wa = (double)wfl[m*65+n];
            double wb = (double)wfl[(64+m)*65+n];
            double wc = (double)wfl[(128+m)*65+n];
            base += wa * ((double)b12[m] + SW1s[m][1])
                  + wb * ((double)b22[m] + SW2s[m][2])
                  + wc * (double)b31[m];
            d10 += wa * SW1s[m][0];  d12 += wa * SW1s[m][2];
            d20 += wb * SW2s[m][0];  d21 += wb * SW2s[m][1];
            d23 += wb * SW2s[m][3];  d24 += wb * SW2s[m][4];
        }
        double a = base;
        if (p >= 3)   a += d10;
        if (p <= 124) a += d12;
        if (p >= 10)  a += d20;
        if (p >= 5)   a += d21;
        if (p <= 122) a += d23;
        if (p <= 117) a += d24;
        Be[p * 64 + n] = a;
    }
}

__global__ __launch_bounds__(512, 1) void front(
    const float* __restrict__ x,   const double* __restrict__ T,
    const double* __restrict__ Be, const float* __restrict__ w1,
    const float* __restrict__ b1,
    double* __restrict__ Qg, double* __restrict__ Pg)
{
    const int b  = blockIdx.y;
    const int s0 = blockIdx.x * 16;
    const int t  = threadIdx.x;
    const int lane = t & 63, wave = t >> 6;
    const int kq = wave & 3, ph = wave >> 2;

    __shared__ float  xl[CIN][37];
    __shared__ float  E[176 * 16];
    __shared__ float  w1L[128 * 65];
    __shared__ double red [4][16][64];
    __shared__ double redP[4][16][64];
    __shared__ double h[64 * 18];
    __shared__ int    COL[11];

    double wT[44];
    #pragma unroll
    for (int kk = 0; kk < 44; ++kk) wT[kk] = T[(kq*44+kk)*64 + lane];

    if (t < 11) { const int offs[11] = {-10,-5,-3,-2,-1,0,1,2,3,5,10}; COL[t] = offs[t] + 10; }
    for (int e = t; e < CIN * 36; e += 512) {
        int c = e / 36, col = e - c * 36;
        int g = s0 - 10 + col;
        xl[c][col] = (g >= 0 && g < SS) ? x[(b * CIN + c) * SS + g] : 0.f;
    }
    for (int e = t; e < 8192; e += 512) {
        int n = e >> 7, k = e & 127;
        w1L[k * 65 + n] = w1[e];
    }
    __syncthreads();                                       // S1
    for (int e = t; e < 2816; e += 512) {
        int k = e >> 4, p = e & 15;
        int c = k / 11, ti = k - c * 11;
        E[e] = xl[c][p + COL[ti]];
    }
    __syncthreads();                                       // S2

    double acc[8];
    #pragma unroll
    for (int q = 0; q < 8; ++q) acc[q] = 0.0;
    #pragma unroll
    for (int kk = 0; kk < 44; ++kk) {
        const float4* dp = (const float4*)(E + (kq*44+kk)*16 + ph*8);
        float4 v0 = dp[0], v1 = dp[1];
        double w = wT[kk];
        acc[0] += (double)v0.x * w; acc[1] += (double)v0.y * w;
        acc[2] += (double)v0.z * w; acc[3] += (double)v0.w * w;
        acc[4] += (double)v1.x * w; acc[5] += (double)v1.y * w;
        acc[6] += (double)v1.z * w; acc[7] += (double)v1.w * w;
    }
    if (kq) { for (int q = 0; q < 8; ++q) red[kq][ph*8+q][lane] = acc[q]; }
    __syncthreads();                                       // S3
    if (!kq) {
        for (int q = 0; q < 8; ++q) {
            int p = ph*8 + q;
            double tot = acc[q] + red[1][p][lane] + red[2][p][lane] + red[3][p][lane]
                       + Be[(s0 + p) * 64 + lane];
            h[lane*18 + p] = tot > 0.0 ? tot : 0.0;
        }
    }
    __syncthreads();                                       // S4

    double aq[8], ap[8];
    #pragma unroll
    for (int q = 0; q < 8; ++q) { aq[q] = 0.0; ap[q] = 0.0; }
    #pragma unroll
    for (int kk = 0; kk < 16; ++kk) {
        int k = kq*16 + kk;
        double q_ = (double)w1L[k * 65 + lane];
        double p_ = (double)w1L[(64 + k) * 65 + lane];
        const double2* hp = (const double2*)(h + k*18 + ph*8);
        double2 d0 = hp[0], d1 = hp[1], d2 = hp[2], d3 = hp[3];
        aq[0] += d0.x*q_; ap[0] += d0.x*p_;  aq[1] += d0.y*q_; ap[1] += d0.y*p_;
        aq[2] += d1.x*q_; ap[2] += d1.x*p_;  aq[3] += d1.y*q_; ap[3] += d1.y*p_;
        aq[4] += d2.x*q_; ap[4] += d2.x*p_;  aq[5] += d2.y*q_; ap[5] += d2.y*p_;
        aq[6] += d3.x*q_; ap[6] += d3.x*p_;  aq[7] += d3.y*q_; ap[7] += d3.y*p_;
    }
    if (kq) {
        for (int q = 0; q < 8; ++q) {
            red [kq][ph*8+q][lane] = aq[q];
            redP[kq][ph*8+q][lane] = ap[q];
        }
    }
    __syncthreads();                                       // S5
    if (!kq) {
        double bv = (double)b1[lane];
        for (int q = 0; q < 8; ++q) {
            int p = ph*8 + q;
            Qg[((long)b*SS + s0 + p)*HH + lane] =
                aq[q] + red[1][p][lane] + red[2][p][lane] + red[3][p][lane];
            Pg[((long)b*SS + s0 + p)*HH + lane] =
                ap[q] + redP[1][p][lane] + redP[2][p][lane] + redP[3][p][lane] + bv;
        }
    }
}

__global__ __launch_bounds__(256) void edges(
    const double* __restrict__ Qg, const double* __restrict__ Pg,
    const float* __restrict__ w2, const float* __restrict__ b2,
    const float* __restrict__ gum, float* __restrict__ out)
{
    const int b  = blockIdx.y;
    const int it = blockIdx.x >> 2;
    const int jt = blockIdx.x & 3;
    const int i0 = it * 16, j0 = jt * 32;
    const int t  = threadIdx.x;
    const int ti = t >> 4, tj = t & 15;
    const int i  = i0 + ti;

    if (j0 + 31 < i0) {
        out[((long)b*SS + i)*SS + j0 + tj]      = 0.f;
        out[((long)b*SS + i)*SS + j0 + tj + 16] = 0.f;
        return;
    }

    __shared__ float Pl[16][68];
    __shared__ float Ql[32][68];
    __shared__ float dwl[64];

    if (t < 64) dwl[t] = w2[t] - w2[64 + t];
    for (int e = t; e < 512; e += 256) {
        int r = e >> 5, c2 = (e & 31) * 2;
        double2 v = *(const double2*)(Pg + ((long)b*SS + i0 + r)*HH + c2);
        Pl[r][c2] = (float)v.x; Pl[r][c2+1] = (float)v.y;
    }
    for (int e = t; e < 1024; e += 256) {
        int r = e >> 5, c2 = (e & 31) * 2;
        double2 v = *(const double2*)(Qg + ((long)b*SS + j0 + r)*HH + c2);
        Ql[r][c2] = (float)v.x; Ql[r][c2+1] = (float)v.y;
    }
    __syncthreads();

    float a0 = 0.f, a1 = 0.f;
    const float4* P0 = (const float4*)&Pl[ti][0];
    const float4* Q0 = (const float4*)&Ql[tj][0];
    const float4* Q1 = (const float4*)&Ql[tj + 16][0];
    const float4* DW = (const float4*)dwl;
#define RDOT(acc, pv, qv, dw) { float v; \
    v = pv.x + qv.x; v = v > 0.f ? v : 0.f; acc += v * dw.x; \
    v = pv.y + qv.y; v = v > 0.f ? v : 0.f; acc += v * dw.y; \
    v = pv.z + qv.z; v = v > 0.f ? v : 0.f; acc += v * dw.z; \
    v = pv.w + qv.w; v = v > 0.f ? v : 0.f; acc += v * dw.w; }
    #pragma unroll
    for (int k4 = 0; k4 < 16; ++k4) {
        float4 pv = P0[k4], dw = DW[k4];
        float4 q0 = Q0[k4], q1 = Q1[k4];
        RDOT(a0, pv, q0, dw)
        RDOT(a1, pv, q1, dw)
    }
#undef RDOT
    const float db2 = b2[0] - b2[1];
    float accs[2] = {a0, a1};
    for (int jj = 0; jj < 2; ++jj) {
        int j = j0 + tj + 16*jj;
        float r = 0.f;
        if (j > i) {
            long e = (long)b*SS*SS + (long)i*SS + j;
            float2 uv = *(const float2*)(gum + e*2);
            float tot = db2 - logf(-logf(uv.x)) + logf(-logf(uv.y)) + accs[jj];
            if (fabsf(tot) < 1e-4f) {
                const double* Prd = Pg + ((long)b*SS + i)*HH;
                const double* Qrd = Qg + ((long)b*SS + j)*HH;
                double s0=0, s1=0, s2=0, s3=0;
                #pragma unroll
                for (int k = 0; k < 64; k += 4) {
                    double v0 = Prd[k]   + Qrd[k];
                    double v1 = Prd[k+1] + Qrd[k+1];
                    double v2 = Prd[k+2] + Qrd[k+2];
                    double v3 = Prd[k+3] + Qrd[k+3];
                    if (v0 > 0.0) s0 += v0 * ((double)w2[k]   - (double)w2[64+k]);
                    if (v1 > 0.0) s1 += v1 * ((double)w2[k+1] - (double)w2[64+k+1]);
                    if (v2 > 0.0) s2 += v2 * ((double)w2[k+2] - (double)w2[64+k+2]);
                    if (v3 > 0.0) s3 += v3 * ((double)w2[k+3] - (double)w2[64+k+3]);
                }
                double accd = (double)b2[0] - (double)b2[1]
                            - log(-log((double)uv.x)) + log(-log((double)uv.y))
                            + ((s0 + s1) + (s2 + s3));
                r = (accd >= 0.0) ? 1.0f : 0.0f;
            } else {
                r = (tot >= 0.f) ? 1.0f : 0.0f;
            }
        }
        out[((long)b*SS + i)*SS + j] = r;
    }
}

extern "C" void kernel_launch(void* const* d_in, const int* in_sizes, int n_in,
                              void* d_out, int out_size, void* d_ws, size_t ws_size,
                              hipStream_t stream) {
    const float* data = (const float*)d_in[0];
    const float* w11  = (const float*)d_in[1];
    const float* b11  = (const float*)d_in[2];
    const float* w12  = (const float*)d_in[3];
    const float* b12  = (const float*)d_in[4];
    const float* w21  = (const float*)d_in[5];
    const float* b21  = (const float*)d_in[6];
    const float* w22  = (const float*)d_in[7];
    const float* b22  = (const float*)d_in[8];
    const float* w31  = (const float*)d_in[9];
    const float* b31  = (const float*)d_in[10];
    const float* wf   = (const float*)d_in[11];
    const float* bf   = (const float*)d_in[12];
    const float* w1   = (const float*)d_in[13];
    const float* b1   = (const float*)d_in[14];
    const float* w2   = (const float*)d_in[15];
    const float* b2   = (const float*)d_in[16];
    const float* gum  = (const float*)d_in[17];
    float* out = (float*)d_out;

    double* T  = (double*)d_ws;             // 11264
    double* Be = T  + 11264;                // 8192
    double* Qg = Be + 8192;                 // 262144
    double* Pg = Qg + 262144;               // 262144

    prep<<<76, 256, 0, stream>>>(w11, w21, w12, w22, w31, wf, bf,
                                 b11, b21, b12, b22, b31, T, Be);
    // MEASUREMENT: 9 identical idempotent launches of front.
    // front_marginal_us = (dur_us - 50.4) / 8.
    for (int rep = 0; rep < 9; ++rep) {
        front<<<dim3(8, BB), 512, 0, stream>>>(data, T, Be, w1, b1, Qg, Pg);
    }
    edges<<<dim3(32, BB), 256, 0, stream>>>(Qg, Pg, w2, b2, gum, out);
}